// Round 2
// baseline (1686.473 us; speedup 1.0000x reference)
//
#include <hip/hip_runtime.h>
#include <hip/hip_bf16.h>
#include <stdint.h>
#include <stddef.h>

// Problem dims
#define NB   16
#define CIN  256
#define HIN  128
#define WIN  128
#define COUT 512
#define HO   64
#define WO   64
#define HBL  129   // blurred spatial size

typedef __attribute__((ext_vector_type(8))) __bf16 bf16x8;
typedef __attribute__((ext_vector_type(4))) float  f32x4;

__device__ __forceinline__ void gld_lds16(const void* g, void* l) {
  __builtin_amdgcn_global_load_lds(
      (const __attribute__((address_space(1))) void*)g,
      (__attribute__((address_space(3))) void*)l, 16, 0, 0);
}

// ---------------------------------------------------------------------------
// Blur: xb[n][i][j][c] (NHWC, bf16) = sum_{u,v} K[u][v] * x[n][c][i+u-2][j+v-2]
// x is fp32 NCHW. Separable: K[u][v] = a[u]*b[v] (exact rank-1).
// One block per (n, output row i). v-pass: 4 coalesced fp32 global reads per
// lane (lanes along j). h-pass: 3x __shfl_down + 4 FMA. Transpose via LDS,
// coalesced NHWC bf16 store (lanes along c).
// ---------------------------------------------------------------------------
__global__ __launch_bounds__(256) void blur_kernel(
    const float* __restrict__ x,
    const float* __restrict__ bk,
    __hip_bfloat16* __restrict__ xb)
{
  __shared__ __hip_bfloat16 lout[CIN * 132];  // [c][j], stride 132

  const int bid  = blockIdx.x;
  const int n    = bid / HBL;
  const int io   = bid % HBL;
  const int t    = threadIdx.x;
  const int wave = t >> 6;
  const int lane = t & 63;

  // separable taps from bk (exact rank-1): a[u]*b[v] == K[u][v]
  const float K11 = bk[5];
  float a[4], b[4];
  #pragma unroll
  for (int u = 0; u < 4; ++u) a[u] = bk[u * 4 + 1] / K11;
  #pragma unroll
  for (int v = 0; v < 4; ++v) b[v] = bk[4 + v];

  // tasks: (window 0..2) x (c 0..255); window w covers jo = w*61 .. w*61+60
  for (int task = wave; task < 3 * CIN; task += 4) {
    const int c     = task & 255;
    const int win   = task >> 8;
    const int jbase = win * 61;

    const int  jm  = jbase + lane - 2;          // vmid column owned by this lane
    const bool jok = (jm >= 0) && (jm < WIN);
    const float* xc = x + ((size_t)(n * CIN + c) * HIN) * WIN;

    float vm = 0.f;
    #pragma unroll
    for (int u = 0; u < 4; ++u) {
      const int r = io + u - 2;
      if (r >= 0 && r < HIN && jok)
        vm += a[u] * xc[r * WIN + jm];
    }
    // h-pass: out(jo = jbase+lane) = sum_v b[v] * vmid[jo+v-2]
    const float v1 = __shfl_down(vm, 1);
    const float v2 = __shfl_down(vm, 2);
    const float v3 = __shfl_down(vm, 3);
    const float out = b[0] * vm + b[1] * v1 + b[2] * v2 + b[3] * v3;

    const int jo = jbase + lane;
    if (lane <= 60 && jo < HBL)
      lout[c * 132 + jo] = __float2bfloat16(out);
  }

  __syncthreads();

  // write full NHWC row: xb[((n*129 + io)*129 + j)*256 + c], lanes along c
  const size_t obase = ((size_t)(n * HBL + io)) * HBL * CIN;
  for (int e = t; e < HBL * CIN; e += 256) {
    const int c = e & 255;
    const int j = e >> 8;
    xb[obase + (size_t)j * CIN + c] = lout[c * 132 + j];
  }
}

// ---------------------------------------------------------------------------
// Weight prep: wt[tap][o][c] = bf16(w[o][c][kh][kw])  (unscaled; the 1/48
// scale is folded into the GEMM epilogue in fp32)
// ---------------------------------------------------------------------------
__global__ __launch_bounds__(256) void wprep_kernel(
    const float* __restrict__ w,
    __hip_bfloat16* __restrict__ wt)
{
  const int idx = blockIdx.x * 256 + threadIdx.x;  // [tap][o][c] linear
  if (idx >= 9 * COUT * CIN) return;
  const int c   = idx & (CIN - 1);
  const int o   = (idx >> 8) & (COUT - 1);
  const int tap = idx >> 17;
  wt[idx] = __float2bfloat16(w[(o * CIN + c) * 9 + tap]);
}

// ---------------------------------------------------------------------------
// Implicit GEMM: y[n][o][h][w] = scale * sum_{tap,c} wt[tap][o][c] *
//                                xb[n][2h+kh][2w+kw][c]  + bias[o]
// M = 65536 pixels (BM=128), N = 512 cout (BN=128), K = 9*256 (BK=64).
// m97 structure: global_load_lds width-16 staging with XOR-16B-group swizzle,
// ds_read_b128 fragments, mfma_f32_16x16x32_bf16, 4 waves = 2x2 of 64x64.
// fp32 output + fp32 bias.
// ---------------------------------------------------------------------------
__global__ void gemm_kernel(
    const __hip_bfloat16* __restrict__ xb,    // [16][129][129][256]
    const __hip_bfloat16* __restrict__ wt,    // [9][512][256]
    const float* __restrict__ bias,           // [512]
    float* __restrict__ y)                    // [16][512][64][64]
{
  __shared__ __hip_bfloat16 sW[128 * 64];  // [o_local][k] rows of 128 B
  __shared__ __hip_bfloat16 sX[128 * 64];  // [pix_local][k]

  const int t    = threadIdx.x;
  const int wave = t >> 6;
  const int lane = t & 63;
  const int bid  = blockIdx.x;
  const int nb   = bid & 3;    // 4 N-blocks
  const int mb   = bid >> 2;   // 512 M-blocks
  const int o0   = nb * 128;
  const int p0   = mb * 128;   // 128 pixels: (h0,h0+1) x w=0..63 of image imgn
  const int imgn = p0 >> 12;
  const int h0   = (p0 >> 6) & 63;

  const int lane_r = lane >> 3;  // staging row within 8-row issue
  const int lane_g = lane & 7;   // 16B group

  f32x4 acc[4][4];
  #pragma unroll
  for (int ai = 0; ai < 4; ++ai)
    #pragma unroll
    for (int bi = 0; bi < 4; ++bi)
      acc[ai][bi] = (f32x4){0.f, 0.f, 0.f, 0.f};

  // per-issue staging constants (lane-dependent), swizzled group g = lane_g ^ (r&7)
  long xconst[4], wconst[4];
  #pragma unroll
  for (int s = 0; s < 4; ++s) {
    const int r  = (wave * 4 + s) * 8 + lane_r;
    const int g  = lane_g ^ (r & 7);
    const int hh = h0 + (r >> 6);
    const int ww = r & 63;
    xconst[s] = ((long)(imgn * HBL + 2 * hh) * HBL + 2 * ww) * CIN + g * 8;
    wconst[s] = (long)(o0 + r) * CIN + g * 8;
  }

  const int q   = lane >> 4;
  const int m16 = lane & 15;
  const int ro_base = (wave >> 1) * 64;
  const int rp_base = (wave & 1) * 64;

  for (int tap = 0; tap < 9; ++tap) {
    const long xoff_tap = (long)((tap / 3) * HBL + (tap % 3)) * CIN;
    const long woff_tap = (long)tap * (COUT * CIN);
    for (int cb = 0; cb < CIN; cb += 64) {
      // ---- stage 32 KB via global_load_lds (16B/lane, wave-uniform LDS base)
      #pragma unroll
      for (int s = 0; s < 4; ++s) {
        const int issue = wave * 4 + s;
        gld_lds16(wt + woff_tap + wconst[s] + cb, (char*)sW + issue * 1024);
        gld_lds16(xb + xoff_tap + xconst[s] + cb, (char*)sX + issue * 1024);
      }
      asm volatile("s_waitcnt vmcnt(0)" ::: "memory");
      __syncthreads();

      // ---- compute: 2 x (8 ds_read_b128 + 16 MFMA)
      #pragma unroll
      for (int kk = 0; kk < 2; ++kk) {
        bf16x8 af[4], bfr[4];
        #pragma unroll
        for (int i4 = 0; i4 < 4; ++i4) {
          const int ro = ro_base + i4 * 16 + m16;
          const int ga = (kk * 4 + q) ^ (ro & 7);
          af[i4] = *(const bf16x8*)((const char*)sW + ro * 128 + ga * 16);
          const int rp = rp_base + i4 * 16 + m16;
          const int gb = (kk * 4 + q) ^ (rp & 7);
          bfr[i4] = *(const bf16x8*)((const char*)sX + rp * 128 + gb * 16);
        }
        #pragma unroll
        for (int ai = 0; ai < 4; ++ai)
          #pragma unroll
          for (int bi = 0; bi < 4; ++bi)
            acc[ai][bi] = __builtin_amdgcn_mfma_f32_16x16x32_bf16(
                af[ai], bfr[bi], acc[ai][bi], 0, 0, 0);
      }
      __syncthreads();
    }
  }

  // ---- epilogue: D row = o (quad*4+reg), col = pixel (lane&15); scale + bias
  const float scale = 1.0f / 48.0f;
  #pragma unroll
  for (int ai = 0; ai < 4; ++ai) {
    const int o = o0 + (wave >> 1) * 64 + ai * 16 + q * 4;
    #pragma unroll
    for (int bi = 0; bi < 4; ++bi) {
      const int p  = p0 + (wave & 1) * 64 + bi * 16 + m16;
      const int n  = p >> 12;
      const int hh = (p >> 6) & 63;
      const int ww = p & 63;
      const size_t obase = ((size_t)(n * COUT + o) * HO + hh) * WO + ww;
      #pragma unroll
      for (int rg = 0; rg < 4; ++rg) {
        const float v = acc[ai][bi][rg] * scale + bias[o + rg];
        y[obase + (size_t)rg * (HO * WO)] = v;
      }
    }
  }
}

// ---------------------------------------------------------------------------
extern "C" void kernel_launch(void* const* d_in, const int* in_sizes, int n_in,
                              void* d_out, int out_size, void* d_ws, size_t ws_size,
                              hipStream_t stream) {
  const float* x  = (const float*)d_in[0];
  const float* w  = (const float*)d_in[1];
  const float* bs = (const float*)d_in[2];
  const float* bk = (const float*)d_in[3];
  float* y = (float*)d_out;

  // workspace: xb (NHWC blurred bf16, 136.3 MB) + wt (2.4 MB)
  __hip_bfloat16* xb = (__hip_bfloat16*)d_ws;
  __hip_bfloat16* wt = (__hip_bfloat16*)((char*)d_ws +
                       (size_t)NB * HBL * HBL * CIN * sizeof(__hip_bfloat16));

  hipLaunchKernelGGL(blur_kernel, dim3(NB * HBL), dim3(256), 0, stream, x, bk, xb);
  hipLaunchKernelGGL(wprep_kernel, dim3((9 * COUT * CIN + 255) / 256), dim3(256), 0, stream, w, wt);
  hipLaunchKernelGGL(gemm_kernel, dim3((65536 / 128) * (COUT / 128)), dim3(256), 0, stream,
                     xb, wt, bs, y);
}

// Round 3
// 698.408 us; speedup vs baseline: 2.4147x; 2.4147x over previous
//
#include <hip/hip_runtime.h>
#include <hip/hip_bf16.h>
#include <stdint.h>
#include <stddef.h>

// Problem dims
#define NB   16
#define CIN  256
#define HIN  128
#define WIN  128
#define COUT 512
#define HO   64
#define WO   64
#define HBL  129   // blurred spatial size

typedef __attribute__((ext_vector_type(8))) __bf16 bf16x8;
typedef __attribute__((ext_vector_type(4))) float  f32x4;

__device__ __forceinline__ void gld_lds16(const void* g, void* l) {
  __builtin_amdgcn_global_load_lds(
      (const __attribute__((address_space(1))) void*)g,
      (__attribute__((address_space(3))) void*)l, 16, 0, 0);
}

__device__ __forceinline__ unsigned pack_bf16(float lo, float hi) {
  __hip_bfloat16 l = __float2bfloat16(lo), h = __float2bfloat16(hi);
  unsigned short ul = *(unsigned short*)&l, uh = *(unsigned short*)&h;
  return (unsigned)ul | ((unsigned)uh << 16);
}

// ---------------------------------------------------------------------------
// Blur v2: xb[n][i][j][c] (NHWC bf16) = sum_{u,v} K[u][v]*x[n][c][i+u-2][j+v-2]
// Block = (n, io), 512 threads (8 waves). Each half-wave owns one channel:
// lane g in [0,32) loads float4 covering cols 4g..4g+3 of 4 input rows
// (row validity is block-uniform -> folded into taps a[u], no divergence).
// v-pass in registers, h-pass via 3 shuffles. LDS [c][j] stride 130 hw
// (2-way banks = free). Store phase: 4x b32 LDS reads + repack -> two
// coalesced 512-B uint2 global stores per wave-instr.
// ---------------------------------------------------------------------------
__global__ __launch_bounds__(512) void blur_kernel(
    const float* __restrict__ x,
    const float* __restrict__ bk,
    __hip_bfloat16* __restrict__ xb)
{
  __shared__ __hip_bfloat16 lout[CIN * 130];  // 66560 B

  const int bid  = blockIdx.x;
  const int n    = bid / HBL;
  const int io   = bid % HBL;
  const int t    = threadIdx.x;
  const int wave = t >> 6;
  const int lane = t & 63;
  const int half = lane >> 5;   // channel within pair
  const int g    = lane & 31;   // 4-col group

  // separable taps (exact rank-1): a[u]*b[v] == K[u][v]
  const float K11 = bk[5];
  float a[4], b[4];
  #pragma unroll
  for (int u = 0; u < 4; ++u) a[u] = bk[u * 4 + 1] / K11;
  #pragma unroll
  for (int v = 0; v < 4; ++v) b[v] = bk[4 + v];

  int rr[4];
  #pragma unroll
  for (int u = 0; u < 4; ++u) {
    int r = io - 2 + u;
    if (r < 0 || r >= HIN) { a[u] = 0.f; r = 0; }  // uniform: fold into tap
    rr[u] = r;
  }

  #pragma unroll 2
  for (int cb = wave * 2; cb < CIN; cb += 16) {
    const int c = cb + half;
    const float4* xr = (const float4*)(x + ((size_t)(n * CIN + c) * HIN) * WIN);
    float4 vm = {0.f, 0.f, 0.f, 0.f};
    #pragma unroll
    for (int u = 0; u < 4; ++u) {
      const float4 rv = xr[rr[u] * 32 + g];
      vm.x += a[u] * rv.x; vm.y += a[u] * rv.y;
      vm.z += a[u] * rv.z; vm.w += a[u] * rv.w;
    }
    float vmm2 = __shfl_up(vm.z, 1);    // vmid[4g-2]
    float vmm1 = __shfl_up(vm.w, 1);    // vmid[4g-1]
    float vmp4 = __shfl_down(vm.x, 1);  // vmid[4g+4]
    if (g == 0)  { vmm2 = 0.f; vmm1 = 0.f; }
    if (g == 31) { vmp4 = 0.f; }
    const float o0 = b[0]*vmm2 + b[1]*vmm1 + b[2]*vm.x + b[3]*vm.y;
    const float o1 = b[0]*vmm1 + b[1]*vm.x + b[2]*vm.y + b[3]*vm.z;
    const float o2 = b[0]*vm.x + b[1]*vm.y + b[2]*vm.z + b[3]*vm.w;
    const float o3 = b[0]*vm.y + b[1]*vm.z + b[2]*vm.w + b[3]*vmp4;
    // two b32 writes (stride 130 hw: dword parity differs per c -> b64 would
    // misalign odd c; banks: halves hit disjoint even/odd banks, 2-way = free)
    unsigned* dst = (unsigned*)&lout[c * 130 + 4 * g];
    dst[0] = pack_bf16(o0, o1);
    dst[1] = pack_bf16(o2, o3);
    if (g == 31)  // out[128] = b0*vmid[126] + b1*vmid[127]
      lout[c * 130 + 128] = __float2bfloat16(b[0]*vm.z + b[1]*vm.w);
  }

  __syncthreads();

  // store: lane l covers c=4l..4l+3 at j-pair (2jp, 2jp+1); wave stores 512 B
  const size_t obase = ((size_t)(n * HBL + io)) * HBL * CIN;
  for (int e = t; e < 65 * 64; e += 512) {
    const int jp = e >> 6;
    const int l  = e & 63;
    const unsigned r0 = *(const unsigned*)&lout[(4*l + 0) * 130 + 2*jp];
    const unsigned r1 = *(const unsigned*)&lout[(4*l + 1) * 130 + 2*jp];
    const unsigned r2 = *(const unsigned*)&lout[(4*l + 2) * 130 + 2*jp];
    const unsigned r3 = *(const unsigned*)&lout[(4*l + 3) * 130 + 2*jp];
    uint2 s0, s1;
    s0.x = (r0 & 0xffffu) | (r1 << 16);
    s0.y = (r2 & 0xffffu) | (r3 << 16);
    s1.x = (r0 >> 16) | (r1 & 0xffff0000u);
    s1.y = (r2 >> 16) | (r3 & 0xffff0000u);
    *(uint2*)&xb[obase + (size_t)(2*jp) * CIN + 4*l] = s0;
    if (jp < 64)  // j=129 doesn't exist
      *(uint2*)&xb[obase + (size_t)(2*jp + 1) * CIN + 4*l] = s1;
  }
}

// ---------------------------------------------------------------------------
// Weight prep: wt[tap][o][c] = bf16(w[o][c][kh][kw])  (unscaled; 1/48 folded
// into the GEMM epilogue in fp32)
// ---------------------------------------------------------------------------
__global__ __launch_bounds__(256) void wprep_kernel(
    const float* __restrict__ w,
    __hip_bfloat16* __restrict__ wt)
{
  const int idx = blockIdx.x * 256 + threadIdx.x;  // [tap][o][c] linear
  if (idx >= 9 * COUT * CIN) return;
  const int c   = idx & (CIN - 1);
  const int o   = (idx >> 8) & (COUT - 1);
  const int tap = idx >> 17;
  wt[idx] = __float2bfloat16(w[(o * CIN + c) * 9 + tap]);
}

// ---------------------------------------------------------------------------
// Implicit GEMM: y[n][o][h][w] = scale * sum_{tap,c} wt[tap][o][c] *
//                                xb[n][2h+kh][2w+kw][c]  + bias[o]
// M = 65536 pixels (BM=128), N = 512 cout (BN=128), K = 9*256 (BK=64).
// m97 structure: global_load_lds width-16 staging with XOR-16B-group swizzle,
// ds_read_b128 fragments, mfma_f32_16x16x32_bf16, 4 waves = 2x2 of 64x64.
// ---------------------------------------------------------------------------
__global__ void gemm_kernel(
    const __hip_bfloat16* __restrict__ xb,    // [16][129][129][256]
    const __hip_bfloat16* __restrict__ wt,    // [9][512][256]
    const float* __restrict__ bias,           // [512]
    float* __restrict__ y)                    // [16][512][64][64]
{
  __shared__ __hip_bfloat16 sW[128 * 64];  // [o_local][k] rows of 128 B
  __shared__ __hip_bfloat16 sX[128 * 64];  // [pix_local][k]

  const int t    = threadIdx.x;
  const int wave = t >> 6;
  const int lane = t & 63;
  const int bid  = blockIdx.x;
  const int nb   = bid & 3;    // 4 N-blocks
  const int mb   = bid >> 2;   // 512 M-blocks
  const int o0   = nb * 128;
  const int p0   = mb * 128;   // 128 pixels: (h0,h0+1) x w=0..63 of image imgn
  const int imgn = p0 >> 12;
  const int h0   = (p0 >> 6) & 63;

  const int lane_r = lane >> 3;  // staging row within 8-row issue
  const int lane_g = lane & 7;   // 16B group

  f32x4 acc[4][4];
  #pragma unroll
  for (int ai = 0; ai < 4; ++ai)
    #pragma unroll
    for (int bi = 0; bi < 4; ++bi)
      acc[ai][bi] = (f32x4){0.f, 0.f, 0.f, 0.f};

  // per-issue staging constants (lane-dependent), swizzled group g = lane_g ^ (r&7)
  long xconst[4], wconst[4];
  #pragma unroll
  for (int s = 0; s < 4; ++s) {
    const int r  = (wave * 4 + s) * 8 + lane_r;
    const int g  = lane_g ^ (r & 7);
    const int hh = h0 + (r >> 6);
    const int ww = r & 63;
    xconst[s] = ((long)(imgn * HBL + 2 * hh) * HBL + 2 * ww) * CIN + g * 8;
    wconst[s] = (long)(o0 + r) * CIN + g * 8;
  }

  const int q   = lane >> 4;
  const int m16 = lane & 15;
  const int ro_base = (wave >> 1) * 64;
  const int rp_base = (wave & 1) * 64;

  for (int tap = 0; tap < 9; ++tap) {
    const long xoff_tap = (long)((tap / 3) * HBL + (tap % 3)) * CIN;
    const long woff_tap = (long)tap * (COUT * CIN);
    for (int cb = 0; cb < CIN; cb += 64) {
      // ---- stage 32 KB via global_load_lds (16B/lane, wave-uniform LDS base)
      #pragma unroll
      for (int s = 0; s < 4; ++s) {
        const int issue = wave * 4 + s;
        gld_lds16(wt + woff_tap + wconst[s] + cb, (char*)sW + issue * 1024);
        gld_lds16(xb + xoff_tap + xconst[s] + cb, (char*)sX + issue * 1024);
      }
      asm volatile("s_waitcnt vmcnt(0)" ::: "memory");
      __syncthreads();

      // ---- compute: 2 x (8 ds_read_b128 + 16 MFMA)
      #pragma unroll
      for (int kk = 0; kk < 2; ++kk) {
        bf16x8 af[4], bfr[4];
        #pragma unroll
        for (int i4 = 0; i4 < 4; ++i4) {
          const int ro = ro_base + i4 * 16 + m16;
          const int ga = (kk * 4 + q) ^ (ro & 7);
          af[i4] = *(const bf16x8*)((const char*)sW + ro * 128 + ga * 16);
          const int rp = rp_base + i4 * 16 + m16;
          const int gb = (kk * 4 + q) ^ (rp & 7);
          bfr[i4] = *(const bf16x8*)((const char*)sX + rp * 128 + gb * 16);
        }
        #pragma unroll
        for (int ai = 0; ai < 4; ++ai)
          #pragma unroll
          for (int bi = 0; bi < 4; ++bi)
            acc[ai][bi] = __builtin_amdgcn_mfma_f32_16x16x32_bf16(
                af[ai], bfr[bi], acc[ai][bi], 0, 0, 0);
      }
      __syncthreads();
    }
  }

  // ---- epilogue: D row = o (quad*4+reg), col = pixel (lane&15); scale + bias
  const float scale = 1.0f / 48.0f;
  #pragma unroll
  for (int ai = 0; ai < 4; ++ai) {
    const int o = o0 + (wave >> 1) * 64 + ai * 16 + q * 4;
    #pragma unroll
    for (int bi = 0; bi < 4; ++bi) {
      const int p  = p0 + (wave & 1) * 64 + bi * 16 + m16;
      const int n  = p >> 12;
      const int hh = (p >> 6) & 63;
      const int ww = p & 63;
      const size_t obase = ((size_t)(n * COUT + o) * HO + hh) * WO + ww;
      #pragma unroll
      for (int rg = 0; rg < 4; ++rg) {
        const float v = acc[ai][bi][rg] * scale + bias[o + rg];
        y[obase + (size_t)rg * (HO * WO)] = v;
      }
    }
  }
}

// ---------------------------------------------------------------------------
extern "C" void kernel_launch(void* const* d_in, const int* in_sizes, int n_in,
                              void* d_out, int out_size, void* d_ws, size_t ws_size,
                              hipStream_t stream) {
  const float* x  = (const float*)d_in[0];
  const float* w  = (const float*)d_in[1];
  const float* bs = (const float*)d_in[2];
  const float* bk = (const float*)d_in[3];
  float* y = (float*)d_out;

  // workspace: xb (NHWC blurred bf16, 136.3 MB) + wt (2.4 MB)
  __hip_bfloat16* xb = (__hip_bfloat16*)d_ws;
  __hip_bfloat16* wt = (__hip_bfloat16*)((char*)d_ws +
                       (size_t)NB * HBL * HBL * CIN * sizeof(__hip_bfloat16));

  hipLaunchKernelGGL(blur_kernel, dim3(NB * HBL), dim3(512), 0, stream, x, bk, xb);
  hipLaunchKernelGGL(wprep_kernel, dim3((9 * COUT * CIN + 255) / 256), dim3(256), 0, stream, w, wt);
  hipLaunchKernelGGL(gemm_kernel, dim3((65536 / 128) * (COUT / 128)), dim3(256), 0, stream,
                     xb, wt, bs, y);
}